// Round 9
// baseline (243.765 us; speedup 1.0000x reference)
//
#include <hip/hip_runtime.h>
#include <math.h>

#define BLOCK 256
#define GRID  2048          // 8192 dual-tiles / 2048 = 4 iters per block

typedef _Float16 half8  __attribute__((ext_vector_type(8)));
typedef __fp16   fp16x2 __attribute__((ext_vector_type(2)));   // cvt_pkrtz ret type
typedef float    f32x4  __attribute__((ext_vector_type(4)));
typedef unsigned int uint4v __attribute__((ext_vector_type(4)));

// Output-column permutation: producer layer writes logical out-feat
// phi(nt, i) into MFMA out-slot (nt, i). Then lane (m,q)'s C quads
// (acc[nt][r] = feat phi(nt, q*4+r)) packed pairwise give exactly the
// consumer B-frag halves (feats kt*32 + q*8 + j, j=0..7) with ZERO data
// movement: activations chain lane-locally through registers.
__device__ __forceinline__ int phi(int nt, int m) {
    return ((nt >> 1) << 5) + ((m >> 2) << 3) + ((nt & 1) << 2) + (m & 3);
}

// A-operand weight fragment: lane (m,q) holds A[i=m][k=q*8+j] = w[k][nsrc].
// w row-major [Kreal, N0]; out-of-range k or !valid -> 0.
__device__ __forceinline__ half8 bfragW(const float* __restrict__ w, int N0,
                                        int nsrc, int k0, int Kreal, bool valid) {
    half8 r;
    #pragma unroll
    for (int j = 0; j < 8; j++) {
        int k = k0 + j;
        float v = (valid && k < Kreal) ? w[k * N0 + nsrc] : 0.f;
        r[j] = (_Float16)v;
    }
    return r;
}

// pack 2 f32 -> 1 dword of 2 f16 (v_cvt_pkrtz_f16_f32), as raw uint
__device__ __forceinline__ unsigned pk2u(float a, float b) {
    return __builtin_bit_cast(unsigned, __builtin_amdgcn_cvt_pkrtz(a, b));
}

__device__ __forceinline__ half8 mk8(unsigned a, unsigned b, unsigned c, unsigned d) {
    uint4v t; t[0] = a; t[1] = b; t[2] = c; t[3] = d;
    return __builtin_bit_cast(half8, t);
}

// ---- pack first (4 cvt_pk), relu in f16 (4 v_pk_max_f16) = 8 VALU ----
__device__ __forceinline__ half8 packrelu(f32x4 a, f32x4 b) {
    half8 h = mk8(pk2u(a[0], a[1]), pk2u(a[2], a[3]),
                  pk2u(b[0], b[1]), pk2u(b[2], b[3]));
#if __has_builtin(__builtin_elementwise_max)
    const half8 hz = {0, 0, 0, 0, 0, 0, 0, 0};
    return __builtin_elementwise_max(h, hz);
#else
    half8 r;
    #pragma unroll
    for (int i = 0; i < 8; i++) r[i] = h[i] > (_Float16)0 ? h[i] : (_Float16)0;
    return r;
#endif
}

__device__ __forceinline__ half8 packraw(f32x4 a, f32x4 b) {
    return mk8(pk2u(a[0], a[1]), pk2u(a[2], a[3]),
               pk2u(b[0], b[1]), pk2u(b[2], b[3]));
}

__device__ __forceinline__ half8 cvt8(float4 v0, float4 v1) {
    return mk8(pk2u(v0.x, v0.y), pk2u(v0.z, v0.w),
               pk2u(v1.x, v1.y), pk2u(v1.z, v1.w));
}

#define MFMA(A, B, C) __builtin_amdgcn_mfma_f32_16x16x32_f16((A), (B), (C), 0, 0, 0)
#define SBAR() __builtin_amdgcn_sched_barrier(0)

// ---- round-9: hybrid weight residency. Round-8 showed VALU halving with
// zero wall change -> pipes are in sum-not-max regime and LDS (44 ops/iter,
// ~28us pipe floor/CU) is the tallest term. Move sig0 (first layer: kills
// the lgkmcnt at the critical-path head) and col1 (longest layer, 12 frags)
// into loop-invariant registers (64 VGPRs), loaded once from the staged
// table. LDS ops/iter 44 -> 28 (~18us floor). ~90 live + 64 cached ~= 155
// < 170 cap at (256,3) -> no spill expected (tripwire: WRITE_SIZE).
#define NFRAG  40
#define F_SIG0 0    // 4  frags  [nt]      (also reg-cached)
#define F_COL0 4    // 8  frags  [nt*2+kt]
#define F_VIS0 12   // 8  frags  [nt*2+kt]
#define F_SIG1 20   // 4  frags  [nt*2+kt], nt<2
#define F_VIS1 24   // 2  frags  [kt]
#define F_COL1 26   // 12 frags  [nt*3+kt] (also reg-cached)
#define F_COL2 38   // 2  frags  [kt]

__global__ __launch_bounds__(BLOCK, 3) void nerf_rw(
    const float* __restrict__ x_feat,
    const float* __restrict__ dvec,
    const float* __restrict__ lvec,
    const float* __restrict__ w_sig0,   // [32,64]
    const float* __restrict__ w_sig1,   // [64,16]
    const float* __restrict__ w_col0,   // [64,64]
    const float* __restrict__ w_col1,   // [79,64]
    const float* __restrict__ w_col2,   // [64,3]
    const float* __restrict__ w_vis0,   // [48,64]
    const float* __restrict__ w_vis1,   // [64,1]
    float* __restrict__ out, int n)
{
    const int tid  = threadIdx.x;
    const int wv   = tid >> 6;
    const int lane = tid & 63;
    const int m    = lane & 15;
    const int q    = lane >> 4;
    const bool odd = (q & 1) != 0;

    __shared__ half8 WL[NFRAG * 64];

    const float* dl = (q < 2) ? lvec : dvec;   // SH source for this lane
    const int ntiles = n >> 7;                 // 128 pts per block, 32 per wave

    // ---- issue iter-0 input loads FIRST (in flight during staging) ----
    float4 rxa0, rxa1, rxb0, rxb1;
    float rvx, rvy, rvz;                       // vec3 of OWN SH point only
    {
        const int t0  = blockIdx.x;
        const int pt0 = (t0 << 7) + wv * 32 + m;
        const int pt1 = pt0 + 16;
        const float4* xa = (const float4*)(x_feat + (size_t)pt0 * 32 + q * 8);
        rxa0 = xa[0]; rxa1 = xa[1];
        const float4* xb = (const float4*)(x_feat + (size_t)pt1 * 32 + q * 8);
        rxb0 = xb[0]; rxb1 = xb[1];
        const float* vv = dl + (size_t)(odd ? pt1 : pt0) * 3;
        rvx = vv[0]; rvy = vv[1]; rvz = vv[2];
    }

    // ---------- one-time staging: each wave fills a subset of frags ----------
    if (wv == 0) {
        #pragma unroll
        for (int nt = 0; nt < 4; nt++)
            WL[(F_SIG0 + nt) * 64 + lane] =
                bfragW(w_sig0, 64, phi(nt, m), q * 8, 32, true);
        // sig1 -> geo, widened to 32 out-cols with zero pads (col1 kt=2 layout)
        #pragma unroll
        for (int nt = 0; nt < 2; nt++)
            #pragma unroll
            for (int kt = 0; kt < 2; kt++) {
                int g = ((m >> 2) << 3) + ((nt & 1) << 2) + (m & 3);
                bool valid = ((m >> 2) < 2) && (g < 15);
                WL[(F_SIG1 + nt * 2 + kt) * 64 + lane] =
                    bfragW(w_sig1, 16, g + 1, kt * 32 + q * 8, 64, valid);
            }
        #pragma unroll
        for (int kt = 0; kt < 2; kt++)
            WL[(F_VIS1 + kt) * 64 + lane] =
                bfragW(w_vis1, 1, 0, kt * 32 + q * 8, 64, m == 0);
    } else if (wv == 1) {
        #pragma unroll
        for (int nt = 0; nt < 4; nt++)
            #pragma unroll
            for (int kt = 0; kt < 2; kt++)
                WL[(F_COL0 + nt * 2 + kt) * 64 + lane] =
                    bfragW(w_col0, 64, phi(nt, m), kt * 32 + q * 8, 64, true);
        #pragma unroll
        for (int kt = 0; kt < 2; kt++)
            WL[(F_COL2 + kt) * 64 + lane] =
                bfragW(w_col2, 3, m, kt * 32 + q * 8, 64, m < 3);
    } else if (wv == 2) {
        #pragma unroll
        for (int nt = 0; nt < 4; nt++)
            #pragma unroll
            for (int kt = 0; kt < 2; kt++)   // k rows 48..63 zero (denc unused)
                WL[(F_VIS0 + nt * 2 + kt) * 64 + lane] =
                    bfragW(w_vis0, 64, phi(nt, m), kt * 32 + q * 8, 48, true);
    } else {
        #pragma unroll
        for (int nt = 0; nt < 4; nt++)
            #pragma unroll
            for (int kt = 0; kt < 3; kt++)   // K=79; rows 79..95 zero
                WL[(F_COL1 + nt * 3 + kt) * 64 + lane] =
                    bfragW(w_col1, 64, phi(nt, m), kt * 32 + q * 8, 79, true);
    }
    __syncthreads();
    // Weights are read-only from here: NO barriers in the main loop.

    // ---- reg-cache sig0 (4 frags) + col1 (12 frags) = 64 VGPRs, read once
    //      from the staged table (constant indices only -> stays in regs) ----
    half8 Ws0_0 = WL[(F_SIG0 + 0) * 64 + lane];
    half8 Ws0_1 = WL[(F_SIG0 + 1) * 64 + lane];
    half8 Ws0_2 = WL[(F_SIG0 + 2) * 64 + lane];
    half8 Ws0_3 = WL[(F_SIG0 + 3) * 64 + lane];
    half8 Wc1_0  = WL[(F_COL1 + 0)  * 64 + lane];
    half8 Wc1_1  = WL[(F_COL1 + 1)  * 64 + lane];
    half8 Wc1_2  = WL[(F_COL1 + 2)  * 64 + lane];
    half8 Wc1_3  = WL[(F_COL1 + 3)  * 64 + lane];
    half8 Wc1_4  = WL[(F_COL1 + 4)  * 64 + lane];
    half8 Wc1_5  = WL[(F_COL1 + 5)  * 64 + lane];
    half8 Wc1_6  = WL[(F_COL1 + 6)  * 64 + lane];
    half8 Wc1_7  = WL[(F_COL1 + 7)  * 64 + lane];
    half8 Wc1_8  = WL[(F_COL1 + 8)  * 64 + lane];
    half8 Wc1_9  = WL[(F_COL1 + 9)  * 64 + lane];
    half8 Wc1_10 = WL[(F_COL1 + 10) * 64 + lane];
    half8 Wc1_11 = WL[(F_COL1 + 11) * 64 + lane];

    int wl = lane;   // LDS element offset; made loop-opaque below to stop
                     // LICM from hoisting remaining frag reads into registers.
    #define LW(f) WL[wl + (f) * 64]

    const f32x4 z = {0.f, 0.f, 0.f, 0.f};
    for (int t = blockIdx.x; t < ntiles; t += GRID) {
        asm volatile("" : "+v"(wl));     // block LICM/CSE of LW() across iters

        const int pt0 = (t << 7) + wv * 32 + m;   // chain A point
        const int pt1 = pt0 + 16;                 // chain B point

        // ---- convert current x inputs -> frags ----
        half8 fA0 = cvt8(rxa0, rxa1);
        half8 fB0 = cvt8(rxb0, rxb1);

        // ---- SH: ONE full sh16 of own point, lane-pair half-swap via
        //      ds_swizzle xor-16 (q even: own=A, q odd: own=B) ----
        half8 fA1, fB1;
        {
            float sx = rvx, sy = rvy, sz = rvz;
            float xx = sx * sx, yy = sy * sy, zz = sz * sz;
            float xy = sx * sy, yz = sy * sz, xz = sx * sz;
            float e0  = 0.28209479177387814f;
            float e1  = -0.48860251190291987f * sy;
            float e2  = 0.48860251190291987f * sz;
            float e3  = -0.48860251190291987f * sx;
            float e4  = 1.0925484305920792f * xy;
            float e5  = -1.0925484305920792f * yz;
            float e6  = 0.94617469575756f * zz - 0.31539156525252005f;
            float e7  = -1.0925484305920792f * xz;
            float e8  = 0.5462742152960396f * (xx - yy);
            float e9  = 0.5900435899266435f * sy * (3.0f * xx - yy);
            float e10 = 2.890611442640554f * xy * sz;
            float e11 = 0.4570457994644657f * sy * (4.0f * zz - xx - yy);
            float e12 = 0.3731763325901154f * sz * (2.0f * zz - 3.0f * xx - 3.0f * yy);
            float e13 = 0.4570457994644657f * sx * (4.0f * zz - xx - yy);
            float e14 = 1.445305721320277f * sz * (xx - yy);
            float e15 = 0.5900435899266435f * sx * (xx - 3.0f * yy);
            unsigned L0 = pk2u(e0, e1),   L1 = pk2u(e2, e3);
            unsigned L2 = pk2u(e4, e5),   L3 = pk2u(e6, e7);
            unsigned H0 = pk2u(e8, e9),   H1 = pk2u(e10, e11);
            unsigned H2 = pk2u(e12, e13), H3 = pk2u(e14, e15);
            unsigned S0 = odd ? L0 : H0, S1 = odd ? L1 : H1;
            unsigned S2 = odd ? L2 : H2, S3 = odd ? L3 : H3;
            unsigned R0 = (unsigned)__builtin_amdgcn_ds_swizzle((int)S0, 0x401F);
            unsigned R1 = (unsigned)__builtin_amdgcn_ds_swizzle((int)S1, 0x401F);
            unsigned R2 = (unsigned)__builtin_amdgcn_ds_swizzle((int)S2, 0x401F);
            unsigned R3 = (unsigned)__builtin_amdgcn_ds_swizzle((int)S3, 0x401F);
            fA1 = mk8(odd ? R0 : L0, odd ? R1 : L1, odd ? R2 : L2, odd ? R3 : L3);
            fB1 = mk8(odd ? H0 : R0, odd ? H1 : R1, odd ? H2 : R2, odd ? H3 : R3);
        }

        // ---- issue prefetch for iter t+GRID (latency hides under body) ----
        {
            int tn = t + GRID;
            int tp = (tn < ntiles) ? tn : t;      // uniform; safe addr on tail
            const int qt0 = (tp << 7) + wv * 32 + m;
            const int qt1 = qt0 + 16;
            const float4* xa = (const float4*)(x_feat + (size_t)qt0 * 32 + q * 8);
            rxa0 = xa[0]; rxa1 = xa[1];
            const float4* xb = (const float4*)(x_feat + (size_t)qt1 * 32 + q * 8);
            rxb0 = xb[0]; rxb1 = xb[1];
            const float* vv = dl + (size_t)(odd ? qt1 : qt0) * 3;
            rvx = vv[0]; rvy = vv[1]; rvz = vv[2];
        }

        half8 w;
        f32x4 aA, aB, bA, bB;

        // ---- sig0: h = relu(x @ w_sig0), K=32 — REGISTER weights: MFMAs
        //      fire the moment fA0/fB0 are built, no lgkmcnt at iter head ----
        aA = MFMA(Ws0_0, fA0, z); aB = MFMA(Ws0_0, fB0, z);
        bA = MFMA(Ws0_1, fA0, z); bB = MFMA(Ws0_1, fB0, z);
        half8 hK0a = packrelu(aA, bA), hK0b = packrelu(aB, bB);
        aA = MFMA(Ws0_2, fA0, z); aB = MFMA(Ws0_2, fB0, z);
        bA = MFMA(Ws0_3, fA0, z); bB = MFMA(Ws0_3, fB0, z);
        half8 hK1a = packrelu(aA, bA), hK1b = packrelu(aB, bB);
        SBAR();

        // ---- sig1 immediately (frees hK*): geo = h @ w_sig1, no relu ----
        w = LW(F_SIG1 + 0); aA = MFMA(w, hK0a, z);  aB = MFMA(w, hK0b, z);
        w = LW(F_SIG1 + 1); aA = MFMA(w, hK1a, aA); aB = MFMA(w, hK1b, aB);
        w = LW(F_SIG1 + 2); bA = MFMA(w, hK0a, z);  bB = MFMA(w, hK0b, z);
        w = LW(F_SIG1 + 3); bA = MFMA(w, hK1a, bA); bB = MFMA(w, hK1b, bB);
        half8 gA = packraw(aA, bA), gB = packraw(aB, bB);
        SBAR();

        // ---- col0: hc = relu([x|lenc|denc] @ w_col0), K=64 ----
        w = LW(F_COL0 + 0); aA = MFMA(w, fA0, z);  aB = MFMA(w, fB0, z);
        w = LW(F_COL0 + 1); aA = MFMA(w, fA1, aA); aB = MFMA(w, fB1, aB);
        w = LW(F_COL0 + 2); bA = MFMA(w, fA0, z);  bB = MFMA(w, fB0, z);
        w = LW(F_COL0 + 3); bA = MFMA(w, fA1, bA); bB = MFMA(w, fB1, bB);
        half8 cK0a = packrelu(aA, bA), cK0b = packrelu(aB, bB);
        w = LW(F_COL0 + 4); aA = MFMA(w, fA0, z);  aB = MFMA(w, fB0, z);
        w = LW(F_COL0 + 5); aA = MFMA(w, fA1, aA); aB = MFMA(w, fB1, aB);
        w = LW(F_COL0 + 6); bA = MFMA(w, fA0, z);  bB = MFMA(w, fB0, z);
        w = LW(F_COL0 + 7); bA = MFMA(w, fA1, bA); bB = MFMA(w, fB1, bB);
        half8 cK1a = packrelu(aA, bA), cK1b = packrelu(aB, bB);
        SBAR();

        // ---- vis0: hv = relu([x|lenc|0] @ w_vis0), K=64 (rows 48+ zero) ----
        w = LW(F_VIS0 + 0); aA = MFMA(w, fA0, z);  aB = MFMA(w, fB0, z);
        w = LW(F_VIS0 + 1); aA = MFMA(w, fA1, aA); aB = MFMA(w, fB1, aB);
        w = LW(F_VIS0 + 2); bA = MFMA(w, fA0, z);  bB = MFMA(w, fB0, z);
        w = LW(F_VIS0 + 3); bA = MFMA(w, fA1, bA); bB = MFMA(w, fB1, bB);
        half8 vK0a = packrelu(aA, bA), vK0b = packrelu(aB, bB);
        w = LW(F_VIS0 + 4); aA = MFMA(w, fA0, z);  aB = MFMA(w, fB0, z);
        w = LW(F_VIS0 + 5); aA = MFMA(w, fA1, aA); aB = MFMA(w, fB1, aB);
        w = LW(F_VIS0 + 6); bA = MFMA(w, fA0, z);  bB = MFMA(w, fB0, z);
        w = LW(F_VIS0 + 7); bA = MFMA(w, fA1, bA); bB = MFMA(w, fB1, bB);
        half8 vK1a = packrelu(aA, bA), vK1b = packrelu(aB, bB);

        // ---- vis1 + sigmoid immediately (frees vK*, and fI* after this) ----
        f32x4 va = z, vb = z;
        w = LW(F_VIS1 + 0); va = MFMA(w, vK0a, va); vb = MFMA(w, vK0b, vb);
        w = LW(F_VIS1 + 1); va = MFMA(w, vK1a, va); vb = MFMA(w, vK1b, vb);
        float visA = 1.f / (1.f + __expf(-va[0]));
        float visB = 1.f / (1.f + __expf(-vb[0]));
        // NO SBAR here: col1 is register-resident — its MFMAs may overlap
        // the sigmoid VALU and vis1's lgkmcnt shadow.

        // ---- col1: h2 = relu([hc|geo] @ w_col1), K=96 — REGISTER weights ----
        aA = MFMA(Wc1_0, cK0a, z);  aB = MFMA(Wc1_0, cK0b, z);
        aA = MFMA(Wc1_1, cK1a, aA); aB = MFMA(Wc1_1, cK1b, aB);
        aA = MFMA(Wc1_2, gA,   aA); aB = MFMA(Wc1_2, gB,   aB);
        bA = MFMA(Wc1_3, cK0a, z);  bB = MFMA(Wc1_3, cK0b, z);
        bA = MFMA(Wc1_4, cK1a, bA); bB = MFMA(Wc1_4, cK1b, bB);
        bA = MFMA(Wc1_5, gA,   bA); bB = MFMA(Wc1_5, gB,   bB);
        half8 h2K0a = packrelu(aA, bA), h2K0b = packrelu(aB, bB);
        aA = MFMA(Wc1_6, cK0a, z);  aB = MFMA(Wc1_6, cK0b, z);
        aA = MFMA(Wc1_7, cK1a, aA); aB = MFMA(Wc1_7, cK1b, aB);
        aA = MFMA(Wc1_8, gA,   aA); aB = MFMA(Wc1_8, gB,   aB);
        bA = MFMA(Wc1_9, cK0a, z);  bB = MFMA(Wc1_9, cK0b, z);
        bA = MFMA(Wc1_10, cK1a, bA); bB = MFMA(Wc1_10, cK1b, bB);
        bA = MFMA(Wc1_11, gA,   bA); bB = MFMA(Wc1_11, gB,   bB);
        half8 h2K1a = packrelu(aA, bA), h2K1b = packrelu(aB, bB);
        SBAR();

        // ---- col2: color = relu(h2 @ w_col2) * vis; rows 0..2 at q==0 ----
        f32x4 ca = z, cb = z;
        w = LW(F_COL2 + 0); ca = MFMA(w, h2K0a, ca); cb = MFMA(w, h2K0b, cb);
        w = LW(F_COL2 + 1); ca = MFMA(w, h2K1a, ca); cb = MFMA(w, h2K1b, cb);
        if (q == 0) {
            float* oa = out + (size_t)pt0 * 3;
            oa[0] = fmaxf(ca[0], 0.f) * visA;
            oa[1] = fmaxf(ca[1], 0.f) * visA;
            oa[2] = fmaxf(ca[2], 0.f) * visA;
            float* ob = out + (size_t)pt1 * 3;
            ob[0] = fmaxf(cb[0], 0.f) * visB;
            ob[1] = fmaxf(cb[1], 0.f) * visB;
            ob[2] = fmaxf(cb[2], 0.f) * visB;
        }
    }
    #undef LW
}

extern "C" void kernel_launch(void* const* d_in, const int* in_sizes, int n_in,
                              void* d_out, int out_size, void* d_ws, size_t ws_size,
                              hipStream_t stream) {
    const float* x_feat = (const float*)d_in[0];
    const float* dvec   = (const float*)d_in[1];
    const float* lvec   = (const float*)d_in[2];
    const float* w_sig0 = (const float*)d_in[3];
    const float* w_sig1 = (const float*)d_in[4];
    const float* w_col0 = (const float*)d_in[5];
    const float* w_col1 = (const float*)d_in[6];
    const float* w_col2 = (const float*)d_in[7];
    const float* w_vis0 = (const float*)d_in[8];
    const float* w_vis1 = (const float*)d_in[9];
    float* out = (float*)d_out;

    const int n = in_sizes[0] / 32;   // N points (1048576: multiple of 128)
    nerf_rw<<<GRID, BLOCK, 0, stream>>>(x_feat, dvec, lvec,
                                        w_sig0, w_sig1, w_col0, w_col1,
                                        w_col2, w_vis0, w_vis1, out, n);
}

// Round 10
// 243.282 us; speedup vs baseline: 1.0020x; 1.0020x over previous
//
#include <hip/hip_runtime.h>
#include <math.h>

#define BLOCK 512           // 8 waves share ONE 40KiB weight table
#define GRID  1024          // 4096 tiles / 1024 = 4 iters per block

typedef _Float16 half8  __attribute__((ext_vector_type(8)));
typedef __fp16   fp16x2 __attribute__((ext_vector_type(2)));   // cvt_pkrtz ret type
typedef float    f32x4  __attribute__((ext_vector_type(4)));
typedef unsigned int uint4v __attribute__((ext_vector_type(4)));

// Output-column permutation: producer layer writes logical out-feat
// phi(nt, i) into MFMA out-slot (nt, i). Then lane (m,q)'s C quads
// (acc[nt][r] = feat phi(nt, q*4+r)) packed pairwise give exactly the
// consumer B-frag halves (feats kt*32 + q*8 + j, j=0..7) with ZERO data
// movement: activations chain lane-locally through registers.
__device__ __forceinline__ int phi(int nt, int m) {
    return ((nt >> 1) << 5) + ((m >> 2) << 3) + ((nt & 1) << 2) + (m & 3);
}

// A-operand weight fragment: lane (m,q) holds A[i=m][k=q*8+j] = w[k][nsrc].
// w row-major [Kreal, N0]; out-of-range k or !valid -> 0.
__device__ __forceinline__ half8 bfragW(const float* __restrict__ w, int N0,
                                        int nsrc, int k0, int Kreal, bool valid) {
    half8 r;
    #pragma unroll
    for (int j = 0; j < 8; j++) {
        int k = k0 + j;
        float v = (valid && k < Kreal) ? w[k * N0 + nsrc] : 0.f;
        r[j] = (_Float16)v;
    }
    return r;
}

// pack 2 f32 -> 1 dword of 2 f16 (v_cvt_pkrtz_f16_f32), as raw uint
__device__ __forceinline__ unsigned pk2u(float a, float b) {
    return __builtin_bit_cast(unsigned, __builtin_amdgcn_cvt_pkrtz(a, b));
}

__device__ __forceinline__ half8 mk8(unsigned a, unsigned b, unsigned c, unsigned d) {
    uint4v t; t[0] = a; t[1] = b; t[2] = c; t[3] = d;
    return __builtin_bit_cast(half8, t);
}

// ---- pack first (4 cvt_pk), relu in f16 (4 v_pk_max_f16) = 8 VALU ----
__device__ __forceinline__ half8 packrelu(f32x4 a, f32x4 b) {
    half8 h = mk8(pk2u(a[0], a[1]), pk2u(a[2], a[3]),
                  pk2u(b[0], b[1]), pk2u(b[2], b[3]));
#if __has_builtin(__builtin_elementwise_max)
    const half8 hz = {0, 0, 0, 0, 0, 0, 0, 0};
    return __builtin_elementwise_max(h, hz);
#else
    half8 r;
    #pragma unroll
    for (int i = 0; i < 8; i++) r[i] = h[i] > (_Float16)0 ? h[i] : (_Float16)0;
    return r;
#endif
}

__device__ __forceinline__ half8 packraw(f32x4 a, f32x4 b) {
    return mk8(pk2u(a[0], a[1]), pk2u(a[2], a[3]),
               pk2u(b[0], b[1]), pk2u(b[2], b[3]));
}

__device__ __forceinline__ half8 cvt8(float4 v0, float4 v1) {
    return mk8(pk2u(v0.x, v0.y), pk2u(v0.z, v0.w),
               pk2u(v1.x, v1.y), pk2u(v1.z, v1.w));
}

#define MFMA(A, B, C) __builtin_amdgcn_mfma_f32_16x16x32_f16((A), (B), (C), 0, 0, 0)
#define SBAR() __builtin_amdgcn_sched_barrier(0)

// ---- round-10: occupancy via block size. The 40KiB weight table is a
// PER-BLOCK cost: 256-thread blocks cap the CU at 3 blocks x 4 waves = 12
// waves (36% occ, r5-r8 plateau); 512-thread blocks sharing one table
// allow 3-4 blocks x 8 waves = 24-32 waves/CU. r9 lesson: reg-caching
// frags costs occupancy (VGPR 84 -> 9 waves) and loses; wave count is
// the latency-hider for this serial-chain workload, so buy waves, not
// per-wave ILP. Per-wave structure = r8 exactly. (512,2): 256-reg cap
// constrains nothing; runtime packs blocks until threads/LDS limit (r4
// evidence: bounds are a floor guarantee, not an occupancy cap).
#define NFRAG  40
#define F_SIG0 0    // 4  frags  [nt]
#define F_COL0 4    // 8  frags  [nt*2+kt]
#define F_VIS0 12   // 8  frags  [nt*2+kt]
#define F_SIG1 20   // 4  frags  [nt*2+kt], nt<2
#define F_VIS1 24   // 2  frags  [kt]
#define F_COL1 26   // 12 frags  [nt*3+kt]
#define F_COL2 38   // 2  frags  [kt]

__global__ __launch_bounds__(BLOCK, 2) void nerf_b512(
    const float* __restrict__ x_feat,
    const float* __restrict__ dvec,
    const float* __restrict__ lvec,
    const float* __restrict__ w_sig0,   // [32,64]
    const float* __restrict__ w_sig1,   // [64,16]
    const float* __restrict__ w_col0,   // [64,64]
    const float* __restrict__ w_col1,   // [79,64]
    const float* __restrict__ w_col2,   // [64,3]
    const float* __restrict__ w_vis0,   // [48,64]
    const float* __restrict__ w_vis1,   // [64,1]
    float* __restrict__ out, int n)
{
    const int tid  = threadIdx.x;
    const int wv   = tid >> 6;          // 0..7
    const int lane = tid & 63;
    const int m    = lane & 15;
    const int q    = lane >> 4;
    const bool odd = (q & 1) != 0;

    __shared__ half8 WL[NFRAG * 64];

    const float* dl = (q < 2) ? lvec : dvec;   // SH source for this lane
    const int ntiles = n >> 8;                 // 256 pts per block, 32 per wave

    // ---- issue iter-0 input loads FIRST (in flight during staging) ----
    float4 rxa0, rxa1, rxb0, rxb1;
    float rvx, rvy, rvz;                       // vec3 of OWN SH point only
    {
        const int t0  = blockIdx.x;
        const int pt0 = (t0 << 8) + wv * 32 + m;
        const int pt1 = pt0 + 16;
        const float4* xa = (const float4*)(x_feat + (size_t)pt0 * 32 + q * 8);
        rxa0 = xa[0]; rxa1 = xa[1];
        const float4* xb = (const float4*)(x_feat + (size_t)pt1 * 32 + q * 8);
        rxb0 = xb[0]; rxb1 = xb[1];
        const float* vv = dl + (size_t)(odd ? pt1 : pt0) * 3;
        rvx = vv[0]; rvy = vv[1]; rvz = vv[2];
    }

    // ---------- one-time staging: waves 0-3 fill the table, 4-7 skip ----------
    if (wv == 0) {
        #pragma unroll
        for (int nt = 0; nt < 4; nt++)
            WL[(F_SIG0 + nt) * 64 + lane] =
                bfragW(w_sig0, 64, phi(nt, m), q * 8, 32, true);
        // sig1 -> geo, widened to 32 out-cols with zero pads (col1 kt=2 layout)
        #pragma unroll
        for (int nt = 0; nt < 2; nt++)
            #pragma unroll
            for (int kt = 0; kt < 2; kt++) {
                int g = ((m >> 2) << 3) + ((nt & 1) << 2) + (m & 3);
                bool valid = ((m >> 2) < 2) && (g < 15);
                WL[(F_SIG1 + nt * 2 + kt) * 64 + lane] =
                    bfragW(w_sig1, 16, g + 1, kt * 32 + q * 8, 64, valid);
            }
        #pragma unroll
        for (int kt = 0; kt < 2; kt++)
            WL[(F_VIS1 + kt) * 64 + lane] =
                bfragW(w_vis1, 1, 0, kt * 32 + q * 8, 64, m == 0);
    } else if (wv == 1) {
        #pragma unroll
        for (int nt = 0; nt < 4; nt++)
            #pragma unroll
            for (int kt = 0; kt < 2; kt++)
                WL[(F_COL0 + nt * 2 + kt) * 64 + lane] =
                    bfragW(w_col0, 64, phi(nt, m), kt * 32 + q * 8, 64, true);
        #pragma unroll
        for (int kt = 0; kt < 2; kt++)
            WL[(F_COL2 + kt) * 64 + lane] =
                bfragW(w_col2, 3, m, kt * 32 + q * 8, 64, m < 3);
    } else if (wv == 2) {
        #pragma unroll
        for (int nt = 0; nt < 4; nt++)
            #pragma unroll
            for (int kt = 0; kt < 2; kt++)   // k rows 48..63 zero (denc unused)
                WL[(F_VIS0 + nt * 2 + kt) * 64 + lane] =
                    bfragW(w_vis0, 64, phi(nt, m), kt * 32 + q * 8, 48, true);
    } else if (wv == 3) {
        #pragma unroll
        for (int nt = 0; nt < 4; nt++)
            #pragma unroll
            for (int kt = 0; kt < 3; kt++)   // K=79; rows 79..95 zero
                WL[(F_COL1 + nt * 3 + kt) * 64 + lane] =
                    bfragW(w_col1, 64, phi(nt, m), kt * 32 + q * 8, 79, true);
    }
    __syncthreads();
    // Weights are read-only from here: NO barriers in the main loop.

    int wl = lane;   // LDS element offset; made loop-opaque below to stop
                     // LICM from hoisting 40 frag reads back into registers
                     // (160 regs of weights would re-blow the budget).
    #define LW(f) WL[wl + (f) * 64]

    const f32x4 z = {0.f, 0.f, 0.f, 0.f};
    for (int t = blockIdx.x; t < ntiles; t += GRID) {
        asm volatile("" : "+v"(wl));     // block LICM/CSE of LW() across iters

        const int pt0 = (t << 8) + wv * 32 + m;   // chain A point
        const int pt1 = pt0 + 16;                 // chain B point

        // ---- convert current x inputs -> frags ----
        half8 fA0 = cvt8(rxa0, rxa1);
        half8 fB0 = cvt8(rxb0, rxb1);

        // ---- SH: ONE full sh16 of own point, lane-pair half-swap via
        //      ds_swizzle xor-16 (q even: own=A, q odd: own=B) ----
        half8 fA1, fB1;
        {
            float sx = rvx, sy = rvy, sz = rvz;
            float xx = sx * sx, yy = sy * sy, zz = sz * sz;
            float xy = sx * sy, yz = sy * sz, xz = sx * sz;
            float e0  = 0.28209479177387814f;
            float e1  = -0.48860251190291987f * sy;
            float e2  = 0.48860251190291987f * sz;
            float e3  = -0.48860251190291987f * sx;
            float e4  = 1.0925484305920792f * xy;
            float e5  = -1.0925484305920792f * yz;
            float e6  = 0.94617469575756f * zz - 0.31539156525252005f;
            float e7  = -1.0925484305920792f * xz;
            float e8  = 0.5462742152960396f * (xx - yy);
            float e9  = 0.5900435899266435f * sy * (3.0f * xx - yy);
            float e10 = 2.890611442640554f * xy * sz;
            float e11 = 0.4570457994644657f * sy * (4.0f * zz - xx - yy);
            float e12 = 0.3731763325901154f * sz * (2.0f * zz - 3.0f * xx - 3.0f * yy);
            float e13 = 0.4570457994644657f * sx * (4.0f * zz - xx - yy);
            float e14 = 1.445305721320277f * sz * (xx - yy);
            float e15 = 0.5900435899266435f * sx * (xx - 3.0f * yy);
            unsigned L0 = pk2u(e0, e1),   L1 = pk2u(e2, e3);
            unsigned L2 = pk2u(e4, e5),   L3 = pk2u(e6, e7);
            unsigned H0 = pk2u(e8, e9),   H1 = pk2u(e10, e11);
            unsigned H2 = pk2u(e12, e13), H3 = pk2u(e14, e15);
            unsigned S0 = odd ? L0 : H0, S1 = odd ? L1 : H1;
            unsigned S2 = odd ? L2 : H2, S3 = odd ? L3 : H3;
            unsigned R0 = (unsigned)__builtin_amdgcn_ds_swizzle((int)S0, 0x401F);
            unsigned R1 = (unsigned)__builtin_amdgcn_ds_swizzle((int)S1, 0x401F);
            unsigned R2 = (unsigned)__builtin_amdgcn_ds_swizzle((int)S2, 0x401F);
            unsigned R3 = (unsigned)__builtin_amdgcn_ds_swizzle((int)S3, 0x401F);
            fA1 = mk8(odd ? R0 : L0, odd ? R1 : L1, odd ? R2 : L2, odd ? R3 : L3);
            fB1 = mk8(odd ? H0 : R0, odd ? H1 : R1, odd ? H2 : R2, odd ? H3 : R3);
        }

        // ---- issue prefetch for iter t+GRID (latency hides under body) ----
        {
            int tn = t + GRID;
            int tp = (tn < ntiles) ? tn : t;      // uniform; safe addr on tail
            const int qt0 = (tp << 8) + wv * 32 + m;
            const int qt1 = qt0 + 16;
            const float4* xa = (const float4*)(x_feat + (size_t)qt0 * 32 + q * 8);
            rxa0 = xa[0]; rxa1 = xa[1];
            const float4* xb = (const float4*)(x_feat + (size_t)qt1 * 32 + q * 8);
            rxb0 = xb[0]; rxb1 = xb[1];
            const float* vv = dl + (size_t)(odd ? qt1 : qt0) * 3;
            rvx = vv[0]; rvy = vv[1]; rvz = vv[2];
        }

        half8 w;
        f32x4 aA, aB, bA, bB;

        // ---- sig0: h = relu(x @ w_sig0), K=32 (no SBAR above: its ds_reads
        //      may overlap input conversion / prefetch issue) ----
        w = LW(F_SIG0 + 0); aA = MFMA(w, fA0, z); aB = MFMA(w, fB0, z);
        w = LW(F_SIG0 + 1); bA = MFMA(w, fA0, z); bB = MFMA(w, fB0, z);
        half8 hK0a = packrelu(aA, bA), hK0b = packrelu(aB, bB);
        w = LW(F_SIG0 + 2); aA = MFMA(w, fA0, z); aB = MFMA(w, fB0, z);
        w = LW(F_SIG0 + 3); bA = MFMA(w, fA0, z); bB = MFMA(w, fB0, z);
        half8 hK1a = packrelu(aA, bA), hK1b = packrelu(aB, bB);
        SBAR();

        // ---- sig1 immediately (frees hK*): geo = h @ w_sig1, no relu ----
        w = LW(F_SIG1 + 0); aA = MFMA(w, hK0a, z);  aB = MFMA(w, hK0b, z);
        w = LW(F_SIG1 + 1); aA = MFMA(w, hK1a, aA); aB = MFMA(w, hK1b, aB);
        w = LW(F_SIG1 + 2); bA = MFMA(w, hK0a, z);  bB = MFMA(w, hK0b, z);
        w = LW(F_SIG1 + 3); bA = MFMA(w, hK1a, bA); bB = MFMA(w, hK1b, bB);
        half8 gA = packraw(aA, bA), gB = packraw(aB, bB);
        SBAR();

        // ---- col0: hc = relu([x|lenc|denc] @ w_col0), K=64 ----
        w = LW(F_COL0 + 0); aA = MFMA(w, fA0, z);  aB = MFMA(w, fB0, z);
        w = LW(F_COL0 + 1); aA = MFMA(w, fA1, aA); aB = MFMA(w, fB1, aB);
        w = LW(F_COL0 + 2); bA = MFMA(w, fA0, z);  bB = MFMA(w, fB0, z);
        w = LW(F_COL0 + 3); bA = MFMA(w, fA1, bA); bB = MFMA(w, fB1, bB);
        half8 cK0a = packrelu(aA, bA), cK0b = packrelu(aB, bB);
        w = LW(F_COL0 + 4); aA = MFMA(w, fA0, z);  aB = MFMA(w, fB0, z);
        w = LW(F_COL0 + 5); aA = MFMA(w, fA1, aA); aB = MFMA(w, fB1, aB);
        w = LW(F_COL0 + 6); bA = MFMA(w, fA0, z);  bB = MFMA(w, fB0, z);
        w = LW(F_COL0 + 7); bA = MFMA(w, fA1, bA); bB = MFMA(w, fB1, bB);
        half8 cK1a = packrelu(aA, bA), cK1b = packrelu(aB, bB);
        SBAR();

        // ---- vis0: hv = relu([x|lenc|0] @ w_vis0), K=64 (rows 48+ zero) ----
        w = LW(F_VIS0 + 0); aA = MFMA(w, fA0, z);  aB = MFMA(w, fB0, z);
        w = LW(F_VIS0 + 1); aA = MFMA(w, fA1, aA); aB = MFMA(w, fB1, aB);
        w = LW(F_VIS0 + 2); bA = MFMA(w, fA0, z);  bB = MFMA(w, fB0, z);
        w = LW(F_VIS0 + 3); bA = MFMA(w, fA1, bA); bB = MFMA(w, fB1, bB);
        half8 vK0a = packrelu(aA, bA), vK0b = packrelu(aB, bB);
        w = LW(F_VIS0 + 4); aA = MFMA(w, fA0, z);  aB = MFMA(w, fB0, z);
        w = LW(F_VIS0 + 5); aA = MFMA(w, fA1, aA); aB = MFMA(w, fB1, aB);
        w = LW(F_VIS0 + 6); bA = MFMA(w, fA0, z);  bB = MFMA(w, fB0, z);
        w = LW(F_VIS0 + 7); bA = MFMA(w, fA1, bA); bB = MFMA(w, fB1, bB);
        half8 vK1a = packrelu(aA, bA), vK1b = packrelu(aB, bB);

        // ---- vis1 + sigmoid immediately (frees vK*, and fI* after this) ----
        f32x4 va = z, vb = z;
        w = LW(F_VIS1 + 0); va = MFMA(w, vK0a, va); vb = MFMA(w, vK0b, vb);
        w = LW(F_VIS1 + 1); va = MFMA(w, vK1a, va); vb = MFMA(w, vK1b, vb);
        float visA = 1.f / (1.f + __expf(-va[0]));
        float visB = 1.f / (1.f + __expf(-vb[0]));
        SBAR();

        // ---- col1: h2 = relu([hc|geo] @ w_col1), K=96 padded ----
        w = LW(F_COL1 + 0);  aA = MFMA(w, cK0a, z);  aB = MFMA(w, cK0b, z);
        w = LW(F_COL1 + 1);  aA = MFMA(w, cK1a, aA); aB = MFMA(w, cK1b, aB);
        w = LW(F_COL1 + 2);  aA = MFMA(w, gA,   aA); aB = MFMA(w, gB,   aB);
        w = LW(F_COL1 + 3);  bA = MFMA(w, cK0a, z);  bB = MFMA(w, cK0b, z);
        w = LW(F_COL1 + 4);  bA = MFMA(w, cK1a, bA); bB = MFMA(w, cK1b, bB);
        w = LW(F_COL1 + 5);  bA = MFMA(w, gA,   bA); bB = MFMA(w, gB,   bB);
        half8 h2K0a = packrelu(aA, bA), h2K0b = packrelu(aB, bB);
        w = LW(F_COL1 + 6);  aA = MFMA(w, cK0a, z);  aB = MFMA(w, cK0b, z);
        w = LW(F_COL1 + 7);  aA = MFMA(w, cK1a, aA); aB = MFMA(w, cK1b, aB);
        w = LW(F_COL1 + 8);  aA = MFMA(w, gA,   aA); aB = MFMA(w, gB,   aB);
        w = LW(F_COL1 + 9);  bA = MFMA(w, cK0a, z);  bB = MFMA(w, cK0b, z);
        w = LW(F_COL1 + 10); bA = MFMA(w, cK1a, bA); bB = MFMA(w, cK1b, bB);
        w = LW(F_COL1 + 11); bA = MFMA(w, gA,   bA); bB = MFMA(w, gB,   bB);
        half8 h2K1a = packrelu(aA, bA), h2K1b = packrelu(aB, bB);
        SBAR();

        // ---- col2: color = relu(h2 @ w_col2) * vis; rows 0..2 at q==0 ----
        f32x4 ca = z, cb = z;
        w = LW(F_COL2 + 0); ca = MFMA(w, h2K0a, ca); cb = MFMA(w, h2K0b, cb);
        w = LW(F_COL2 + 1); ca = MFMA(w, h2K1a, ca); cb = MFMA(w, h2K1b, cb);
        if (q == 0) {
            float* oa = out + (size_t)pt0 * 3;
            oa[0] = fmaxf(ca[0], 0.f) * visA;
            oa[1] = fmaxf(ca[1], 0.f) * visA;
            oa[2] = fmaxf(ca[2], 0.f) * visA;
            float* ob = out + (size_t)pt1 * 3;
            ob[0] = fmaxf(cb[0], 0.f) * visB;
            ob[1] = fmaxf(cb[1], 0.f) * visB;
            ob[2] = fmaxf(cb[2], 0.f) * visB;
        }
    }
    #undef LW
}

extern "C" void kernel_launch(void* const* d_in, const int* in_sizes, int n_in,
                              void* d_out, int out_size, void* d_ws, size_t ws_size,
                              hipStream_t stream) {
    const float* x_feat = (const float*)d_in[0];
    const float* dvec   = (const float*)d_in[1];
    const float* lvec   = (const float*)d_in[2];
    const float* w_sig0 = (const float*)d_in[3];
    const float* w_sig1 = (const float*)d_in[4];
    const float* w_col0 = (const float*)d_in[5];
    const float* w_col1 = (const float*)d_in[6];
    const float* w_col2 = (const float*)d_in[7];
    const float* w_vis0 = (const float*)d_in[8];
    const float* w_vis1 = (const float*)d_in[9];
    float* out = (float*)d_out;

    const int n = in_sizes[0] / 32;   // N points (1048576: multiple of 256)
    nerf_b512<<<GRID, BLOCK, 0, stream>>>(x_feat, dvec, lvec,
                                          w_sig0, w_sig1, w_col0, w_col1,
                                          w_col2, w_vis0, w_vis1, out, n);
}

// Round 11
// 239.747 us; speedup vs baseline: 1.0168x; 1.0147x over previous
//
#include <hip/hip_runtime.h>
#include <math.h>

#define BLOCK 256
#define GRID  2048          // 8192 dual-tiles / 2048 = 4 iters per block

typedef _Float16 half8  __attribute__((ext_vector_type(8)));
typedef __fp16   fp16x2 __attribute__((ext_vector_type(2)));   // cvt_pkrtz ret type
typedef float    f32x4  __attribute__((ext_vector_type(4)));
typedef unsigned int uint4v __attribute__((ext_vector_type(4)));

// Output-column permutation: producer layer writes logical out-feat
// phi(nt, i) into MFMA out-slot (nt, i). Then lane (m,q)'s C quads
// (acc[nt][r] = feat phi(nt, q*4+r)) packed pairwise give exactly the
// consumer B-frag halves (feats kt*32 + q*8 + j, j=0..7) with ZERO data
// movement: activations chain lane-locally through registers.
__device__ __forceinline__ int phi(int nt, int m) {
    return ((nt >> 1) << 5) + ((m >> 2) << 3) + ((nt & 1) << 2) + (m & 3);
}

// A-operand weight fragment: lane (m,q) holds A[i=m][k=q*8+j] = w[k][nsrc].
// w row-major [Kreal, N0]; out-of-range k or !valid -> 0.
__device__ __forceinline__ half8 bfragW(const float* __restrict__ w, int N0,
                                        int nsrc, int k0, int Kreal, bool valid) {
    half8 r;
    #pragma unroll
    for (int j = 0; j < 8; j++) {
        int k = k0 + j;
        float v = (valid && k < Kreal) ? w[k * N0 + nsrc] : 0.f;
        r[j] = (_Float16)v;
    }
    return r;
}

// pack 2 f32 -> 1 dword of 2 f16 (v_cvt_pkrtz_f16_f32), as raw uint
__device__ __forceinline__ unsigned pk2u(float a, float b) {
    return __builtin_bit_cast(unsigned, __builtin_amdgcn_cvt_pkrtz(a, b));
}

__device__ __forceinline__ half8 mk8(unsigned a, unsigned b, unsigned c, unsigned d) {
    uint4v t; t[0] = a; t[1] = b; t[2] = c; t[3] = d;
    return __builtin_bit_cast(half8, t);
}

// ---- pack first (4 cvt_pk), relu in f16 (4 v_pk_max_f16) = 8 VALU ----
__device__ __forceinline__ half8 packrelu(f32x4 a, f32x4 b) {
    half8 h = mk8(pk2u(a[0], a[1]), pk2u(a[2], a[3]),
                  pk2u(b[0], b[1]), pk2u(b[2], b[3]));
#if __has_builtin(__builtin_elementwise_max)
    const half8 hz = {0, 0, 0, 0, 0, 0, 0, 0};
    return __builtin_elementwise_max(h, hz);
#else
    half8 r;
    #pragma unroll
    for (int i = 0; i < 8; i++) r[i] = h[i] > (_Float16)0 ? h[i] : (_Float16)0;
    return r;
#endif
}

__device__ __forceinline__ half8 packraw(f32x4 a, f32x4 b) {
    return mk8(pk2u(a[0], a[1]), pk2u(a[2], a[3]),
               pk2u(b[0], b[1]), pk2u(b[2], b[3]));
}

__device__ __forceinline__ half8 cvt8(float4 v0, float4 v1) {
    return mk8(pk2u(v0.x, v0.y), pk2u(v0.z, v0.w),
               pk2u(v1.x, v1.y), pk2u(v1.z, v1.w));
}

#define MFMA(A, B, C) __builtin_amdgcn_mfma_f32_16x16x32_f16((A), (B), (C), 0, 0, 0)

// ---- round-11: free the scheduler. Occupancy is pinned at 12 waves/CU in
// EVERY config (r5-r10: block 256/512, bounds 2/3/4) -> buying waves is a
// dead end; the lever is per-wave stalls. The per-layer sched_barrier(0)
// fences (added in r3 to contain spilling whose TRUE cause — addressable
// e[16] — was removed in r5) serialize ds_read->lgkmcnt->MFMA 7x per iter.
// Removing them lets the scheduler hoist weight reads across layers
// (sig0/col0/vis0: 40 mutually-independent MFMAs off the same inputs),
// overlapping LDS latency with MFMA issue. Tripwire: WRITE_SIZE >30MB =
// allocator spilled under the 170-reg cap -> restore partial fences.
#define NFRAG  40
#define F_SIG0 0    // 4  frags  [nt]
#define F_COL0 4    // 8  frags  [nt*2+kt]
#define F_VIS0 12   // 8  frags  [nt*2+kt]
#define F_SIG1 20   // 4  frags  [nt*2+kt], nt<2
#define F_VIS1 24   // 2  frags  [kt]
#define F_COL1 26   // 12 frags  [nt*3+kt]
#define F_COL2 38   // 2  frags  [kt]

__global__ __launch_bounds__(BLOCK, 3) void nerf_ns(
    const float* __restrict__ x_feat,
    const float* __restrict__ dvec,
    const float* __restrict__ lvec,
    const float* __restrict__ w_sig0,   // [32,64]
    const float* __restrict__ w_sig1,   // [64,16]
    const float* __restrict__ w_col0,   // [64,64]
    const float* __restrict__ w_col1,   // [79,64]
    const float* __restrict__ w_col2,   // [64,3]
    const float* __restrict__ w_vis0,   // [48,64]
    const float* __restrict__ w_vis1,   // [64,1]
    float* __restrict__ out, int n)
{
    const int tid  = threadIdx.x;
    const int wv   = tid >> 6;
    const int lane = tid & 63;
    const int m    = lane & 15;
    const int q    = lane >> 4;
    const bool odd = (q & 1) != 0;

    __shared__ half8 WL[NFRAG * 64];

    const float* dl = (q < 2) ? lvec : dvec;   // SH source for this lane
    const int ntiles = n >> 7;                 // 128 pts per block, 32 per wave

    // ---- issue iter-0 input loads FIRST (in flight during staging) ----
    float4 rxa0, rxa1, rxb0, rxb1;
    float rvx, rvy, rvz;                       // vec3 of OWN SH point only
    {
        const int t0  = blockIdx.x;
        const int pt0 = (t0 << 7) + wv * 32 + m;
        const int pt1 = pt0 + 16;
        const float4* xa = (const float4*)(x_feat + (size_t)pt0 * 32 + q * 8);
        rxa0 = xa[0]; rxa1 = xa[1];
        const float4* xb = (const float4*)(x_feat + (size_t)pt1 * 32 + q * 8);
        rxb0 = xb[0]; rxb1 = xb[1];
        const float* vv = dl + (size_t)(odd ? pt1 : pt0) * 3;
        rvx = vv[0]; rvy = vv[1]; rvz = vv[2];
    }

    // ---------- one-time staging: each wave fills a subset of frags ----------
    if (wv == 0) {
        #pragma unroll
        for (int nt = 0; nt < 4; nt++)
            WL[(F_SIG0 + nt) * 64 + lane] =
                bfragW(w_sig0, 64, phi(nt, m), q * 8, 32, true);
        // sig1 -> geo, widened to 32 out-cols with zero pads (col1 kt=2 layout)
        #pragma unroll
        for (int nt = 0; nt < 2; nt++)
            #pragma unroll
            for (int kt = 0; kt < 2; kt++) {
                int g = ((m >> 2) << 3) + ((nt & 1) << 2) + (m & 3);
                bool valid = ((m >> 2) < 2) && (g < 15);
                WL[(F_SIG1 + nt * 2 + kt) * 64 + lane] =
                    bfragW(w_sig1, 16, g + 1, kt * 32 + q * 8, 64, valid);
            }
        #pragma unroll
        for (int kt = 0; kt < 2; kt++)
            WL[(F_VIS1 + kt) * 64 + lane] =
                bfragW(w_vis1, 1, 0, kt * 32 + q * 8, 64, m == 0);
    } else if (wv == 1) {
        #pragma unroll
        for (int nt = 0; nt < 4; nt++)
            #pragma unroll
            for (int kt = 0; kt < 2; kt++)
                WL[(F_COL0 + nt * 2 + kt) * 64 + lane] =
                    bfragW(w_col0, 64, phi(nt, m), kt * 32 + q * 8, 64, true);
        #pragma unroll
        for (int kt = 0; kt < 2; kt++)
            WL[(F_COL2 + kt) * 64 + lane] =
                bfragW(w_col2, 3, m, kt * 32 + q * 8, 64, m < 3);
    } else if (wv == 2) {
        #pragma unroll
        for (int nt = 0; nt < 4; nt++)
            #pragma unroll
            for (int kt = 0; kt < 2; kt++)   // k rows 48..63 zero (denc unused)
                WL[(F_VIS0 + nt * 2 + kt) * 64 + lane] =
                    bfragW(w_vis0, 64, phi(nt, m), kt * 32 + q * 8, 48, true);
    } else {
        #pragma unroll
        for (int nt = 0; nt < 4; nt++)
            #pragma unroll
            for (int kt = 0; kt < 3; kt++)   // K=79; rows 79..95 zero
                WL[(F_COL1 + nt * 3 + kt) * 64 + lane] =
                    bfragW(w_col1, 64, phi(nt, m), kt * 32 + q * 8, 79, true);
    }
    __syncthreads();
    // Weights are read-only from here: NO barriers in the main loop.

    int wl = lane;   // LDS element offset; made loop-opaque below to stop
                     // cross-iteration CSE of the 40 frag reads (within-
                     // iteration hoisting is allowed and wanted).
    #define LW(f) WL[wl + (f) * 64]

    const f32x4 z = {0.f, 0.f, 0.f, 0.f};
    for (int t = blockIdx.x; t < ntiles; t += GRID) {
        asm volatile("" : "+v"(wl));     // block LICM/CSE of LW() across iters

        const int pt0 = (t << 7) + wv * 32 + m;   // chain A point
        const int pt1 = pt0 + 16;                 // chain B point

        // ---- convert current x inputs -> frags ----
        half8 fA0 = cvt8(rxa0, rxa1);
        half8 fB0 = cvt8(rxb0, rxb1);

        // ---- SH: ONE full sh16 of own point, lane-pair half-swap via
        //      ds_swizzle xor-16 (q even: own=A, q odd: own=B) ----
        half8 fA1, fB1;
        {
            float sx = rvx, sy = rvy, sz = rvz;
            float xx = sx * sx, yy = sy * sy, zz = sz * sz;
            float xy = sx * sy, yz = sy * sz, xz = sx * sz;
            float e0  = 0.28209479177387814f;
            float e1  = -0.48860251190291987f * sy;
            float e2  = 0.48860251190291987f * sz;
            float e3  = -0.48860251190291987f * sx;
            float e4  = 1.0925484305920792f * xy;
            float e5  = -1.0925484305920792f * yz;
            float e6  = 0.94617469575756f * zz - 0.31539156525252005f;
            float e7  = -1.0925484305920792f * xz;
            float e8  = 0.5462742152960396f * (xx - yy);
            float e9  = 0.5900435899266435f * sy * (3.0f * xx - yy);
            float e10 = 2.890611442640554f * xy * sz;
            float e11 = 0.4570457994644657f * sy * (4.0f * zz - xx - yy);
            float e12 = 0.3731763325901154f * sz * (2.0f * zz - 3.0f * xx - 3.0f * yy);
            float e13 = 0.4570457994644657f * sx * (4.0f * zz - xx - yy);
            float e14 = 1.445305721320277f * sz * (xx - yy);
            float e15 = 0.5900435899266435f * sx * (xx - 3.0f * yy);
            unsigned L0 = pk2u(e0, e1),   L1 = pk2u(e2, e3);
            unsigned L2 = pk2u(e4, e5),   L3 = pk2u(e6, e7);
            unsigned H0 = pk2u(e8, e9),   H1 = pk2u(e10, e11);
            unsigned H2 = pk2u(e12, e13), H3 = pk2u(e14, e15);
            unsigned S0 = odd ? L0 : H0, S1 = odd ? L1 : H1;
            unsigned S2 = odd ? L2 : H2, S3 = odd ? L3 : H3;
            unsigned R0 = (unsigned)__builtin_amdgcn_ds_swizzle((int)S0, 0x401F);
            unsigned R1 = (unsigned)__builtin_amdgcn_ds_swizzle((int)S1, 0x401F);
            unsigned R2 = (unsigned)__builtin_amdgcn_ds_swizzle((int)S2, 0x401F);
            unsigned R3 = (unsigned)__builtin_amdgcn_ds_swizzle((int)S3, 0x401F);
            fA1 = mk8(odd ? R0 : L0, odd ? R1 : L1, odd ? R2 : L2, odd ? R3 : L3);
            fB1 = mk8(odd ? H0 : R0, odd ? H1 : R1, odd ? H2 : R2, odd ? H3 : R3);
        }

        // ---- issue prefetch for iter t+GRID (latency hides under body) ----
        {
            int tn = t + GRID;
            int tp = (tn < ntiles) ? tn : t;      // uniform; safe addr on tail
            const int qt0 = (tp << 7) + wv * 32 + m;
            const int qt1 = qt0 + 16;
            const float4* xa = (const float4*)(x_feat + (size_t)qt0 * 32 + q * 8);
            rxa0 = xa[0]; rxa1 = xa[1];
            const float4* xb = (const float4*)(x_feat + (size_t)qt1 * 32 + q * 8);
            rxb0 = xb[0]; rxb1 = xb[1];
            const float* vv = dl + (size_t)(odd ? qt1 : qt0) * 3;
            rvx = vv[0]; rvy = vv[1]; rvz = vv[2];
        }

        half8 w;
        f32x4 aA, aB, bA, bB;

        // ---- sig0: h = relu(x @ w_sig0), K=32 ----
        w = LW(F_SIG0 + 0); aA = MFMA(w, fA0, z); aB = MFMA(w, fB0, z);
        w = LW(F_SIG0 + 1); bA = MFMA(w, fA0, z); bB = MFMA(w, fB0, z);
        half8 hK0a = packrelu(aA, bA), hK0b = packrelu(aB, bB);
        w = LW(F_SIG0 + 2); aA = MFMA(w, fA0, z); aB = MFMA(w, fB0, z);
        w = LW(F_SIG0 + 3); bA = MFMA(w, fA0, z); bB = MFMA(w, fB0, z);
        half8 hK1a = packrelu(aA, bA), hK1b = packrelu(aB, bB);

        // ---- sig1 immediately (frees hK*): geo = h @ w_sig1, no relu ----
        w = LW(F_SIG1 + 0); aA = MFMA(w, hK0a, z);  aB = MFMA(w, hK0b, z);
        w = LW(F_SIG1 + 1); aA = MFMA(w, hK1a, aA); aB = MFMA(w, hK1b, aB);
        w = LW(F_SIG1 + 2); bA = MFMA(w, hK0a, z);  bB = MFMA(w, hK0b, z);
        w = LW(F_SIG1 + 3); bA = MFMA(w, hK1a, bA); bB = MFMA(w, hK1b, bB);
        half8 gA = packraw(aA, bA), gB = packraw(aB, bB);

        // ---- col0: hc = relu([x|lenc|denc] @ w_col0), K=64 ----
        w = LW(F_COL0 + 0); aA = MFMA(w, fA0, z);  aB = MFMA(w, fB0, z);
        w = LW(F_COL0 + 1); aA = MFMA(w, fA1, aA); aB = MFMA(w, fB1, aB);
        w = LW(F_COL0 + 2); bA = MFMA(w, fA0, z);  bB = MFMA(w, fB0, z);
        w = LW(F_COL0 + 3); bA = MFMA(w, fA1, bA); bB = MFMA(w, fB1, bB);
        half8 cK0a = packrelu(aA, bA), cK0b = packrelu(aB, bB);
        w = LW(F_COL0 + 4); aA = MFMA(w, fA0, z);  aB = MFMA(w, fB0, z);
        w = LW(F_COL0 + 5); aA = MFMA(w, fA1, aA); aB = MFMA(w, fB1, aB);
        w = LW(F_COL0 + 6); bA = MFMA(w, fA0, z);  bB = MFMA(w, fB0, z);
        w = LW(F_COL0 + 7); bA = MFMA(w, fA1, bA); bB = MFMA(w, fB1, bB);
        half8 cK1a = packrelu(aA, bA), cK1b = packrelu(aB, bB);

        // ---- vis0: hv = relu([x|lenc|0] @ w_vis0), K=64 (rows 48+ zero) ----
        w = LW(F_VIS0 + 0); aA = MFMA(w, fA0, z);  aB = MFMA(w, fB0, z);
        w = LW(F_VIS0 + 1); aA = MFMA(w, fA1, aA); aB = MFMA(w, fB1, aB);
        w = LW(F_VIS0 + 2); bA = MFMA(w, fA0, z);  bB = MFMA(w, fB0, z);
        w = LW(F_VIS0 + 3); bA = MFMA(w, fA1, bA); bB = MFMA(w, fB1, bB);
        half8 vK0a = packrelu(aA, bA), vK0b = packrelu(aB, bB);
        w = LW(F_VIS0 + 4); aA = MFMA(w, fA0, z);  aB = MFMA(w, fB0, z);
        w = LW(F_VIS0 + 5); aA = MFMA(w, fA1, aA); aB = MFMA(w, fB1, aB);
        w = LW(F_VIS0 + 6); bA = MFMA(w, fA0, z);  bB = MFMA(w, fB0, z);
        w = LW(F_VIS0 + 7); bA = MFMA(w, fA1, bA); bB = MFMA(w, fB1, bB);
        half8 vK1a = packrelu(aA, bA), vK1b = packrelu(aB, bB);

        // ---- vis1 + sigmoid immediately (frees vK*, and fI* after this) ----
        f32x4 va = z, vb = z;
        w = LW(F_VIS1 + 0); va = MFMA(w, vK0a, va); vb = MFMA(w, vK0b, vb);
        w = LW(F_VIS1 + 1); va = MFMA(w, vK1a, va); vb = MFMA(w, vK1b, vb);
        float visA = 1.f / (1.f + __expf(-va[0]));
        float visB = 1.f / (1.f + __expf(-vb[0]));

        // ---- col1: h2 = relu([hc|geo] @ w_col1), K=96 padded ----
        w = LW(F_COL1 + 0);  aA = MFMA(w, cK0a, z);  aB = MFMA(w, cK0b, z);
        w = LW(F_COL1 + 1);  aA = MFMA(w, cK1a, aA); aB = MFMA(w, cK1b, aB);
        w = LW(F_COL1 + 2);  aA = MFMA(w, gA,   aA); aB = MFMA(w, gB,   aB);
        w = LW(F_COL1 + 3);  bA = MFMA(w, cK0a, z);  bB = MFMA(w, cK0b, z);
        w = LW(F_COL1 + 4);  bA = MFMA(w, cK1a, bA); bB = MFMA(w, cK1b, bB);
        w = LW(F_COL1 + 5);  bA = MFMA(w, gA,   bA); bB = MFMA(w, gB,   bB);
        half8 h2K0a = packrelu(aA, bA), h2K0b = packrelu(aB, bB);
        w = LW(F_COL1 + 6);  aA = MFMA(w, cK0a, z);  aB = MFMA(w, cK0b, z);
        w = LW(F_COL1 + 7);  aA = MFMA(w, cK1a, aA); aB = MFMA(w, cK1b, aB);
        w = LW(F_COL1 + 8);  aA = MFMA(w, gA,   aA); aB = MFMA(w, gB,   aB);
        w = LW(F_COL1 + 9);  bA = MFMA(w, cK0a, z);  bB = MFMA(w, cK0b, z);
        w = LW(F_COL1 + 10); bA = MFMA(w, cK1a, bA); bB = MFMA(w, cK1b, bB);
        w = LW(F_COL1 + 11); bA = MFMA(w, gA,   bA); bB = MFMA(w, gB,   bB);
        half8 h2K1a = packrelu(aA, bA), h2K1b = packrelu(aB, bB);

        // ---- col2: color = relu(h2 @ w_col2) * vis; rows 0..2 at q==0 ----
        f32x4 ca = z, cb = z;
        w = LW(F_COL2 + 0); ca = MFMA(w, h2K0a, ca); cb = MFMA(w, h2K0b, cb);
        w = LW(F_COL2 + 1); ca = MFMA(w, h2K1a, ca); cb = MFMA(w, h2K1b, cb);
        if (q == 0) {
            float* oa = out + (size_t)pt0 * 3;
            oa[0] = fmaxf(ca[0], 0.f) * visA;
            oa[1] = fmaxf(ca[1], 0.f) * visA;
            oa[2] = fmaxf(ca[2], 0.f) * visA;
            float* ob = out + (size_t)pt1 * 3;
            ob[0] = fmaxf(cb[0], 0.f) * visB;
            ob[1] = fmaxf(cb[1], 0.f) * visB;
            ob[2] = fmaxf(cb[2], 0.f) * visB;
        }
    }
    #undef LW
}

extern "C" void kernel_launch(void* const* d_in, const int* in_sizes, int n_in,
                              void* d_out, int out_size, void* d_ws, size_t ws_size,
                              hipStream_t stream) {
    const float* x_feat = (const float*)d_in[0];
    const float* dvec   = (const float*)d_in[1];
    const float* lvec   = (const float*)d_in[2];
    const float* w_sig0 = (const float*)d_in[3];
    const float* w_sig1 = (const float*)d_in[4];
    const float* w_col0 = (const float*)d_in[5];
    const float* w_col1 = (const float*)d_in[6];
    const float* w_col2 = (const float*)d_in[7];
    const float* w_vis0 = (const float*)d_in[8];
    const float* w_vis1 = (const float*)d_in[9];
    float* out = (float*)d_out;

    const int n = in_sizes[0] / 32;   // N points (1048576: multiple of 128)
    nerf_ns<<<GRID, BLOCK, 0, stream>>>(x_feat, dvec, lvec,
                                        w_sig0, w_sig1, w_col0, w_col1,
                                        w_col2, w_vis0, w_vis1, out, n);
}